// Round 3
// baseline (36.408 us; speedup 1.0000x reference)
//
#include <hip/hip_runtime.h>

// REM generator: out[h][i][j], 8 x 2048 x 2048 f32.
// out[h][i][j] = V_h[i-j] for i>=j else 0, with -eye baked into V_h[0];
//   V_h[d] = (d % n == 0) ? F[Lc(d)] * G[Lc(d/n)] : 0,  Lc(x) = (x<=200)?x:0.
// Kernel 1 (8 blocks): build phase-split reversed float4 windows into d_ws:
//   R[h][p][m] = {V[4m+p], V[4m+p-1], V[4m+p-2], V[4m+p-3]}  (OOB -> 0)
// Kernel 2 (pure stream): one cached 16B table load + one NT dwordx4 store.

#define CAP  200
#define T    2048
#define ROWS 8

typedef float f32x4 __attribute__((ext_vector_type(4)));

__device__ __forceinline__ float ipow_f(float base, int L) {
    float mag = powf(fabsf(base), (float)L);
    float sgn = ((L & 1) && (base < 0.0f)) ? -1.0f : 1.0f;
    return sgn * mag;
}

__global__ __launch_bounds__(256) void build_kernel(
    const float* __restrict__ eta,
    const float* __restrict__ nu,
    const float* __restrict__ theta,
    f32x4* __restrict__ R_ws)
{
    __shared__ float V[T];
    const int h   = blockIdx.x;
    const int tid = threadIdx.x;

    for (int k = tid; k < T; k += 256) {
        const int Lk = (k <= CAP) ? k : 0;
        float val;
        switch (h) {
        case 0: case 1:
            val = ipow_f(tanhf(eta[h]), Lk);
            break;
        case 2: {                                  // dilate(lam2^L, 4)
            if (k & 3) { val = 0.0f; }
            else { int q = k >> 2; int Lq = (q <= CAP) ? q : 0;
                   val = ipow_f(tanhf(eta[2]), Lq); }
        } break;
        case 3: case 4: {                          // gam^L * cos(theta*L)
            float gm = 1.0f / (1.0f + expf(-nu[h - 3]));
            val = ipow_f(gm, Lk) * cosf(theta[h - 3] * (float)Lk);
        } break;
        case 5: {                                  // gam2^L * sin(theta2*L)
            float gm = 1.0f / (1.0f + expf(-nu[2]));
            val = ipow_f(gm, Lk) * sinf(theta[2] * (float)Lk);
        } break;
        case 6: {                                  // dilate(cos(t3*L),3) * cos(t3*L)
            int q = k / 3;
            if (k - q * 3) { val = 0.0f; }
            else { int Lq = (q <= CAP) ? q : 0;
                   val = cosf(theta[3] * (float)Lk) * cosf(theta[3] * (float)Lq); }
        } break;
        default: {                                 // dilate(sin(t4*L),2) * sin(t4*L)
            if (k & 1) { val = 0.0f; }
            else { int q = k >> 1; int Lq = (q <= CAP) ? q : 0;
                   val = sinf(theta[4] * (float)Lk) * sinf(theta[4] * (float)Lq); }
        } break;
        }
        if (k == 0) val -= 1.0f;                   // bake -eye into V[0]
        V[k] = val;
    }
    __syncthreads();

    const f32x4* V4 = reinterpret_cast<const f32x4*>(V);
    #pragma unroll
    for (int it = 0; it < 8; ++it) {
        const int p = it >> 1;
        const int m = ((it & 1) << 8) + tid;       // 0..511
        f32x4 A = V4[m];
        f32x4 B = (m > 0) ? V4[m - 1] : (f32x4){0.f, 0.f, 0.f, 0.f};
        f32x4 w;
        if      (p == 0) w = (f32x4){A.x, B.w, B.z, B.y};
        else if (p == 1) w = (f32x4){A.y, A.x, B.w, B.z};
        else if (p == 2) w = (f32x4){A.z, A.y, A.x, B.w};
        else             w = (f32x4){A.w, A.z, A.y, A.x};
        R_ws[((h << 2) + p) * 512 + m] = w;
    }
}

__global__ __launch_bounds__(256) void stream_kernel(
    const f32x4* __restrict__ R_ws,
    f32x4* __restrict__ out4)
{
    const int h    = blockIdx.y;
    const int row0 = blockIdx.x * ROWS;
    const int tid  = threadIdx.x;
    const f32x4 zero = {0.f, 0.f, 0.f, 0.f};
    f32x4* outh = out4 + (size_t)h * (T * 512);

    #pragma unroll 8
    for (int k2 = 0; k2 < ROWS * 2; ++k2) {
        const int r  = k2 >> 1;
        const int c4 = ((k2 & 1) << 8) + tid;
        const int i  = row0 + r;
        const int p  = i & 3;                      // wave-uniform
        const int m  = (i >> 2) - c4;              // descending, coalesced
        f32x4 t = R_ws[((h << 2) + p) * 512 + (m > 0 ? m : 0)];
        if (m < 0) t = zero;
        __builtin_nontemporal_store(t, &outh[(size_t)i * 512 + c4]);
    }
}

// Fallback (round-1 proven kernel) if ws_size is too small for the table.
__global__ __launch_bounds__(256) void rem_fallback(
    const float* __restrict__ eta,
    const float* __restrict__ nu,
    const float* __restrict__ theta,
    float* __restrict__ out)
{
    __shared__ float F[256];
    __shared__ float G[256];
    const int h    = blockIdx.y;
    const int row0 = blockIdx.x * 8;
    const int tid  = threadIdx.x;
    if (tid <= CAP) {
        const int t = tid;
        float f = 1.0f, g = 1.0f;
        switch (h) {
            case 0: f = ipow_f(tanhf(eta[0]), t); break;
            case 1: f = ipow_f(tanhf(eta[1]), t); break;
            case 2: g = ipow_f(tanhf(eta[2]), t); break;
            case 3: { float gm = 1.0f/(1.0f+expf(-nu[0]));
                      f = ipow_f(gm, t) * cosf(theta[0]*(float)t); } break;
            case 4: { float gm = 1.0f/(1.0f+expf(-nu[1]));
                      f = ipow_f(gm, t) * cosf(theta[1]*(float)t); } break;
            case 5: { float gm = 1.0f/(1.0f+expf(-nu[2]));
                      f = ipow_f(gm, t) * sinf(theta[2]*(float)t); } break;
            case 6: f = cosf(theta[3]*(float)t); g = f; break;
            case 7: f = sinf(theta[4]*(float)t); g = f; break;
        }
        F[t] = f; G[t] = g;
    }
    __syncthreads();
    const int      n_tab[8]   = {1,1,4,1,1,1,3,2};
    const unsigned mag_tab[8] = {65536u,65536u,16384u,65536u,65536u,65536u,21846u,32768u};
    const int      n   = n_tab[h];
    const unsigned mag = mag_tab[h];
    f32x4* out4 = reinterpret_cast<f32x4*>(out) + (size_t)h * (T * 512u);
    #pragma unroll
    for (int k = 0; k < 16; ++k) {
        int f4 = tid + k * 256;
        int r  = f4 >> 9;
        int c4 = f4 & 511;
        int i  = row0 + r;
        int j  = c4 << 2;
        f32x4 vv;
        #pragma unroll
        for (int e = 0; e < 4; ++e) {
            int dd = i - (j + e);
            float val = 0.0f;
            if (dd >= 0) {
                unsigned q   = ((unsigned)dd * mag) >> 16;
                int      rem = dd - (int)(q * (unsigned)n);
                if (rem == 0) {
                    int L  = (dd     <= CAP) ? dd     : 0;
                    int Lq = ((int)q <= CAP) ? (int)q : 0;
                    val = F[L] * G[Lq];
                }
                if (dd == 0) val -= 1.0f;
            }
            vv[e] = val;
        }
        out4[(size_t)i * 512 + c4] = vv;
    }
}

extern "C" void kernel_launch(void* const* d_in, const int* in_sizes, int n_in,
                              void* d_out, int out_size, void* d_ws, size_t ws_size,
                              hipStream_t stream) {
    (void)in_sizes; (void)n_in; (void)out_size;
    const float* eta   = (const float*)d_in[0];
    const float* nu    = (const float*)d_in[1];
    const float* theta = (const float*)d_in[2];

    if (ws_size >= 8u * 4u * 512u * sizeof(f32x4)) {
        f32x4* R_ws = (f32x4*)d_ws;
        build_kernel<<<dim3(8, 1, 1), 256, 0, stream>>>(eta, nu, theta, R_ws);
        stream_kernel<<<dim3(T / ROWS, 8, 1), 256, 0, stream>>>(
            R_ws, (f32x4*)d_out);
    } else {
        rem_fallback<<<dim3(T / 8, 8, 1), 256, 0, stream>>>(
            eta, nu, theta, (float*)d_out);
    }
}

// Round 4
// 26.134 us; speedup vs baseline: 1.3931x; 1.3931x over previous
//
#include <hip/hip_runtime.h>

// REM generator: out[h][i][j], 8 x 2048 x 2048 f32.
// out[h][i][j] = V_h[i-j] for i>=j else 0, -eye baked into V_h[0];
//   V_h[d] = (d % n == 0) ? F[Lc(d)] * G[Lc(d/n)] : 0,  Lc(x) = (x<=200)?x:0.
// Single kernel: cheap table build (exp2f, no powf) -> phase-split reversed
// float4 windows R[p][m] = {V[4m+p],V[4m+p-1],V[4m+p-2],V[4m+p-3]} in LDS ->
// pure store stream: one conflict-free ds_read_b128 + one dwordx4 store per f4.

#define CAP  200
#define T    2048
#define ROWS 16

typedef float f32x4 __attribute__((ext_vector_type(4)));

__device__ __forceinline__ float powL(float c /*log2|base|*/, bool neg, int L) {
    // base^L for integer L>=0: exact 1 at L==0 (covers base==0 -> c==-inf)
    if (L == 0) return 1.0f;
    float v = exp2f((float)L * c);
    return (neg && (L & 1)) ? -v : v;
}

__global__ __launch_bounds__(256) void rem_kernel(
    const float* __restrict__ eta,
    const float* __restrict__ nu,
    const float* __restrict__ theta,
    f32x4* __restrict__ out4)
{
    __shared__ float V[T];           // 8 KB
    __shared__ f32x4 R[4 * 512];     // 32 KB

    const int h    = blockIdx.y;
    const int row0 = blockIdx.x * ROWS;
    const int tid  = threadIdx.x;

    // ---- per-head scalars (hoisted: one log2f instead of per-entry powf) ----
    float cA = 0.0f, th = 0.0f;
    bool  neg = false;
    if (h < 3) {
        float lam = tanhf(eta[h]);
        cA = log2f(fabsf(lam));
        neg = (lam < 0.0f);
    } else if (h < 6) {
        float gm = 1.0f / (1.0f + expf(-nu[h - 3]));
        cA = log2f(gm);
        th = theta[h - 3];
    } else {
        th = theta[h - 3];           // h6 -> theta[3], h7 -> theta[4]
    }

    // ---- stage 1: V[k] (8 entries/thread, ~1 TRANS each) ----
    for (int k = tid; k < T; k += 256) {
        const int Lk = (k <= CAP) ? k : 0;
        float val;
        switch (h) {
        case 0: case 1:
            val = powL(cA, neg, Lk);
            break;
        case 2: {                                  // dilate(lam2^L, 4)
            if (k & 3) { val = 0.0f; }
            else { int q = k >> 2; int Lq = (q <= CAP) ? q : 0;
                   val = powL(cA, neg, Lq); }
        } break;
        case 3: case 4:                            // gam^L * cos(theta*L)
            val = powL(cA, false, Lk) * cosf(th * (float)Lk);
            break;
        case 5:                                    // gam2^L * sin(theta2*L)
            val = powL(cA, false, Lk) * sinf(th * (float)Lk);
            break;
        case 6: {                                  // dilate(cos,3) * cos
            unsigned q = (unsigned)k / 3u;
            if ((unsigned)k != 3u * q) { val = 0.0f; }
            else { int Lq = ((int)q <= CAP) ? (int)q : 0;
                   val = cosf(th * (float)Lk) * cosf(th * (float)Lq); }
        } break;
        default: {                                 // dilate(sin,2) * sin
            if (k & 1) { val = 0.0f; }
            else { int q = k >> 1; int Lq = (q <= CAP) ? q : 0;
                   val = sinf(th * (float)Lk) * sinf(th * (float)Lq); }
        } break;
        }
        if (k == 0) val -= 1.0f;                   // bake -eye into V[0]
        V[k] = val;
    }
    __syncthreads();

    // ---- stage 2: phase-split reversed windows ----
    const f32x4* V4 = reinterpret_cast<const f32x4*>(V);
    #pragma unroll
    for (int it = 0; it < 8; ++it) {
        const int p = it >> 1;                     // compile-time phase
        const int m = ((it & 1) << 8) + tid;       // 0..511
        f32x4 A = V4[m];
        f32x4 B = (m > 0) ? V4[m - 1] : (f32x4){0.f, 0.f, 0.f, 0.f};
        f32x4 w;
        if      (p == 0) w = (f32x4){A.x, B.w, B.z, B.y};
        else if (p == 1) w = (f32x4){A.y, A.x, B.w, B.z};
        else if (p == 2) w = (f32x4){A.z, A.y, A.x, B.w};
        else             w = (f32x4){A.w, A.z, A.y, A.x};
        R[p * 512 + m] = w;
    }
    __syncthreads();

    // ---- stage 3: store stream (1 b128 LDS read + 1 dwordx4 store per f4) ----
    f32x4* outh = out4 + (size_t)h * (T * 512);
    const f32x4 zero = {0.f, 0.f, 0.f, 0.f};
    #pragma unroll 8
    for (int k2 = 0; k2 < ROWS * 2; ++k2) {
        const int r  = k2 >> 1;
        const int c4 = ((k2 & 1) << 8) + tid;
        const int i  = row0 + r;
        const int p  = i & 3;                      // wave-uniform
        const int m  = (i >> 2) - c4;              // lane stride -1: conflict-free
        f32x4 t = R[p * 512 + ((m > 0) ? m : 0)];
        if (m < 0) t = zero;
        outh[(size_t)i * 512 + c4] = t;
    }
}

extern "C" void kernel_launch(void* const* d_in, const int* in_sizes, int n_in,
                              void* d_out, int out_size, void* d_ws, size_t ws_size,
                              hipStream_t stream) {
    (void)in_sizes; (void)n_in; (void)d_ws; (void)ws_size; (void)out_size;
    const float* eta   = (const float*)d_in[0];
    const float* nu    = (const float*)d_in[1];
    const float* theta = (const float*)d_in[2];

    dim3 grid(T / ROWS, 8, 1);   // 128 x 8 = 1024 blocks; 40 KB LDS -> 4 blocks/CU
    rem_kernel<<<grid, 256, 0, stream>>>(eta, nu, theta, (f32x4*)d_out);
}